// Round 1
// baseline (645.434 us; speedup 1.0000x reference)
//
#include <hip/hip_runtime.h>
#include <cstdint>
#include <math.h>

typedef _Float16 f16;
typedef f16 f16x8 __attribute__((ext_vector_type(8)));
typedef f16 f16x4 __attribute__((ext_vector_type(4)));
typedef float f32x4 __attribute__((ext_vector_type(4)));

#define BATCH 2
#define TSEQ 4096
#define WID 2048
#define LRU 2048
#define NHEAD 8
#define HDIM 256
#define MTOT (BATCH * TSEQ)   // 8192
#define CT 64                 // scan chunk length
#define NC (TSEQ / CT)        // 64 chunks

// ---------- async global -> LDS, 16B per lane ----------
__device__ __forceinline__ void gl2lds16(const f16* g, f16* l) {
  __builtin_amdgcn_global_load_lds(
      (__attribute__((address_space(1))) uint32_t*)(uintptr_t)g,
      (__attribute__((address_space(3))) uint32_t*)(uint32_t)(uintptr_t)l,
      16, 0, 0);
}

__device__ __forceinline__ float sigmoidf_(float x) { return 1.f / (1.f + expf(-x)); }

// ---------- elementwise cast fp32 -> f16 (x4 vectorized) ----------
__global__ void cast_f32_f16_kernel(const float* __restrict__ in, f16* __restrict__ out, int n4) {
  int i = blockIdx.x * 256 + threadIdx.x;
  if (i >= n4) return;
  float4 v = ((const float4*)in)[i];
  f16x4 o = { (f16)v.x, (f16)v.y, (f16)v.z, (f16)v.w };
  ((f16x4*)out)[i] = o;
}

// ---------- transpose + cast: in [R,C] fp32 -> out [C,R] f16, batched over z ----------
__global__ void transpose_cast_kernel(const float* __restrict__ in, f16* __restrict__ out,
                                      int R, int C, long long inStride, long long outStride) {
  __shared__ float tile[32][33];
  const float* ib = in + (long long)blockIdx.z * inStride;
  f16* ob = out + (long long)blockIdx.z * outStride;
  int c0 = blockIdx.x * 32, r0 = blockIdx.y * 32;
  int tx = threadIdx.x, ty = threadIdx.y;  // (32,8)
#pragma unroll
  for (int i = 0; i < 32; i += 8)
    tile[ty + i][tx] = ib[(long long)(r0 + ty + i) * C + c0 + tx];
  __syncthreads();
#pragma unroll
  for (int i = 0; i < 32; i += 8)
    ob[(long long)(c0 + ty + i) * R + r0 + tx] = (f16)tile[tx][ty + i];
}

// ---------- GEMM: C[M,N] = A[M,K] @ BT[N,K]^T + bias ----------
// A, BT row-major f16. EPI=0: Cf fp32 = v + bias. EPI=1: Ch f16 = gelu_tanh(v + bias).
// 128x128 tile, BK=32, 256 threads (4 waves, 2x2 of 64x64), global_load_lds staging.
template <int EPI>
__global__ __launch_bounds__(256, 2) void gemm_bt(
    const f16* __restrict__ A, const f16* __restrict__ BT, const float* __restrict__ bias,
    float* __restrict__ Cf, f16* __restrict__ Ch, int M, int N, int K) {
  __shared__ __align__(16) f16 As[128 * 32];
  __shared__ __align__(16) f16 Bs[128 * 32];
  const int m0 = blockIdx.x * 128, n0 = blockIdx.y * 128;
  const int t = threadIdx.x;
  const int lane = t & 63, wave = t >> 6;
  const int wr = (wave >> 1) * 64, wc = (wave & 1) * 64;
  const int l15 = lane & 15, quad = lane >> 4;
  const int srow = t >> 2, scol = (t & 3) * 8;

  const f16* Ag = A + (long long)(m0 + srow) * K + scol;
  const f16* Bg = BT + (long long)(n0 + srow) * K + scol;
  f16* As0 = &As[t * 8]; f16* As1 = &As[64 * 32 + t * 8];
  f16* Bs0 = &Bs[t * 8]; f16* Bs1 = &Bs[64 * 32 + t * 8];

  f32x4 acc[4][4] = {};
  for (int k0 = 0; k0 < K; k0 += 32) {
    gl2lds16(Ag, As0); gl2lds16(Ag + (long long)64 * K, As1);
    gl2lds16(Bg, Bs0); gl2lds16(Bg + (long long)64 * K, Bs1);
    Ag += 32; Bg += 32;
    __syncthreads();  // drains vmcnt before barrier
    f16x8 af[4], bf[4];
#pragma unroll
    for (int i = 0; i < 4; ++i)
      af[i] = *(const f16x8*)&As[(wr + i * 16 + l15) * 32 + quad * 8];
#pragma unroll
    for (int j = 0; j < 4; ++j)
      bf[j] = *(const f16x8*)&Bs[(wc + j * 16 + l15) * 32 + quad * 8];
#pragma unroll
    for (int i = 0; i < 4; ++i)
#pragma unroll
      for (int j = 0; j < 4; ++j)
        acc[i][j] = __builtin_amdgcn_mfma_f32_16x16x32_f16(af[i], bf[j], acc[i][j], 0, 0, 0);
    __syncthreads();
  }
  // epilogue: C/D frag mapping col=lane&15, row=quad*4+reg (m89/m91-verified)
#pragma unroll
  for (int i = 0; i < 4; ++i) {
#pragma unroll
    for (int j = 0; j < 4; ++j) {
      const int col = n0 + wc + j * 16 + l15;
      const float bv = bias[col];
      const int row0 = m0 + wr + i * 16 + quad * 4;
#pragma unroll
      for (int r = 0; r < 4; ++r) {
        float v = acc[i][j][r] + bv;
        long long off = (long long)(row0 + r) * N + col;
        if (EPI == 0) {
          Cf[off] = v;
        } else {
          float u = v + 0.044715f * v * v * v;
          float g = 0.5f * v * (1.f + tanhf(0.7978845608028654f * u));
          Ch[off] = (f16)g;
        }
      }
    }
  }
}

// ---------- causal depthwise temporal conv (TW=4), writes f16 ----------
__global__ void conv_kernel(const float* __restrict__ xb, const float* __restrict__ cw,
                            const float* __restrict__ cb, f16* __restrict__ convh) {
  int l = (blockIdx.x * 256 + threadIdx.x) * 4;
  int m = blockIdx.y;              // b*T + t
  int tpos = m & (TSEQ - 1);
  float4 acc = *(const float4*)&cb[l];
#pragma unroll
  for (int d = 0; d < 4; ++d) {    // delay d: weight conv_w[3-d]
    if (tpos >= d) {
      float4 xv = *(const float4*)&xb[(long long)(m - d) * LRU + l];
      float4 wv = *(const float4*)&cw[(3 - d) * LRU + l];
      acc.x += wv.x * xv.x; acc.y += wv.y * xv.y;
      acc.z += wv.z * xv.z; acc.w += wv.w * xv.w;
    }
  }
  f16x4 o = { (f16)acc.x, (f16)acc.y, (f16)acc.z, (f16)acc.w };
  *(f16x4*)&convh[(long long)m * LRU + l] = o;
}

// ---------- block-diag dual gate GEMM + RG-LRU elementwise epilogue ----------
// grid.y: head = y>>1, n-half = y&1. A = convh [MTOT, LRU] with k-offset head*HDIM.
// BiT/BaT: [L, HDIM] f16 (row n = h*HD+e holds w[h,:,e]). Outputs a_masked, normed fp32.
__global__ __launch_bounds__(256, 2) void gates_kernel(
    const f16* __restrict__ Ah, const f16* __restrict__ BiT, const f16* __restrict__ BaT,
    const float* __restrict__ ib, const float* __restrict__ ab,
    const float* __restrict__ a_param, const int* __restrict__ segpos,
    float* __restrict__ am, float* __restrict__ normed) {
  __shared__ __align__(16) f16 As[128 * 32];
  __shared__ __align__(16) f16 Bi[128 * 32];
  __shared__ __align__(16) f16 Ba[128 * 32];
  const int m0 = blockIdx.x * 128;
  const int h = blockIdx.y >> 1;
  const int ncol0 = h * HDIM + (blockIdx.y & 1) * 128;  // global L-col of tile origin
  const int t = threadIdx.x;
  const int lane = t & 63, wave = t >> 6;
  const int wr = (wave >> 1) * 64, wc = (wave & 1) * 64;
  const int l15 = lane & 15, quad = lane >> 4;
  const int srow = t >> 2, scol = (t & 3) * 8;

  const f16* Ag = Ah + (long long)(m0 + srow) * LRU + h * HDIM + scol;
  const f16* Big = BiT + (long long)(ncol0 + srow) * HDIM + scol;
  const f16* Bag = BaT + (long long)(ncol0 + srow) * HDIM + scol;

  f32x4 ci[4][4] = {};
  f32x4 ca[4][4] = {};
  for (int k0 = 0; k0 < HDIM; k0 += 32) {
    gl2lds16(Ag, &As[t * 8]);  gl2lds16(Ag + (long long)64 * LRU, &As[64 * 32 + t * 8]);
    gl2lds16(Big, &Bi[t * 8]); gl2lds16(Big + 64 * HDIM, &Bi[64 * 32 + t * 8]);
    gl2lds16(Bag, &Ba[t * 8]); gl2lds16(Bag + 64 * HDIM, &Ba[64 * 32 + t * 8]);
    Ag += 32; Big += 32; Bag += 32;
    __syncthreads();
    f16x8 af[4], bif[4], baf[4];
#pragma unroll
    for (int i = 0; i < 4; ++i)
      af[i] = *(const f16x8*)&As[(wr + i * 16 + l15) * 32 + quad * 8];
#pragma unroll
    for (int j = 0; j < 4; ++j) {
      bif[j] = *(const f16x8*)&Bi[(wc + j * 16 + l15) * 32 + quad * 8];
      baf[j] = *(const f16x8*)&Ba[(wc + j * 16 + l15) * 32 + quad * 8];
    }
#pragma unroll
    for (int i = 0; i < 4; ++i)
#pragma unroll
      for (int j = 0; j < 4; ++j) {
        ci[i][j] = __builtin_amdgcn_mfma_f32_16x16x32_f16(af[i], bif[j], ci[i][j], 0, 0, 0);
        ca[i][j] = __builtin_amdgcn_mfma_f32_16x16x32_f16(af[i], baf[j], ca[i][j], 0, 0, 0);
      }
    __syncthreads();
  }
#pragma unroll
  for (int i = 0; i < 4; ++i) {
#pragma unroll
    for (int j = 0; j < 4; ++j) {
      const int col = ncol0 + wc + j * 16 + l15;
      const float ibv = ib[col], abv = ab[col];
      const float sp = log1pf(expf(a_param[col]));  // softplus
      const int row0 = m0 + wr + i * 16 + quad * 4;
#pragma unroll
      for (int r = 0; r < 4; ++r) {
        const int row = row0 + r;
        float gx = sigmoidf_(ci[i][j][r] + ibv);
        float ga = sigmoidf_(ca[i][j][r] + abv);
        float la = -8.f * ga * sp;
        float a = expf(la);
        bool rs = (segpos[row] == 0);
        float mult = rs ? 1.f : sqrtf(fmaxf(1.f - expf(2.f * la), 0.f));
        float cv = (float)Ah[(long long)row * LRU + col];
        long long off = (long long)row * LRU + col;
        normed[off] = cv * gx * mult;
        am[off] = rs ? 0.f : a;
      }
    }
  }
}

// ---------- chunked scan pass 1: per-chunk (prod a, partial h) ----------
__global__ void scan1_kernel(const float* __restrict__ am, const float* __restrict__ normed,
                             float* __restrict__ Ac, float* __restrict__ Hc) {
  int l = blockIdx.x * 256 + threadIdx.x;
  int c = blockIdx.y, b = blockIdx.z;
  long long base = ((long long)b * TSEQ + (long long)c * CT) * LRU + l;
  float A = 1.f, hv = 0.f;
#pragma unroll 8
  for (int s = 0; s < CT; ++s) {
    float a = am[base + (long long)s * LRU];
    float x = normed[base + (long long)s * LRU];
    A *= a;
    hv = a * hv + x;
  }
  int o = (b * NC + c) * LRU + l;
  Ac[o] = A;
  Hc[o] = hv;
}

// ---------- pass 2: serial prefix over chunks -> carry-in state per chunk ----------
__global__ void scan2_kernel(const float* __restrict__ Ac, const float* __restrict__ Hc,
                             float* __restrict__ P) {
  int l = blockIdx.x * 256 + threadIdx.x;
  int b = blockIdx.y;
  float hv = 0.f;
#pragma unroll 8
  for (int c = 0; c < NC; ++c) {
    int o = (b * NC + c) * LRU + l;
    P[o] = hv;
    hv = Ac[o] * hv + Hc[o];
  }
}

// ---------- pass 3: apply carry, fuse h*y, emit f16 G for final GEMM ----------
__global__ void scan3_kernel(const float* __restrict__ am, const float* __restrict__ normed,
                             const float* __restrict__ P, const f16* __restrict__ Yh,
                             f16* __restrict__ G) {
  int l = blockIdx.x * 256 + threadIdx.x;
  int c = blockIdx.y, b = blockIdx.z;
  long long base = ((long long)b * TSEQ + (long long)c * CT) * LRU + l;
  float hv = P[(b * NC + c) * LRU + l];
#pragma unroll 4
  for (int s = 0; s < CT; ++s) {
    long long o = base + (long long)s * LRU;
    float a = am[o], x = normed[o];
    hv = a * hv + x;
    G[o] = (f16)(hv * (float)Yh[o]);
  }
}

extern "C" void kernel_launch(void* const* d_in, const int* in_sizes, int n_in,
                              void* d_out, int out_size, void* d_ws, size_t ws_size,
                              hipStream_t stream) {
  (void)in_sizes; (void)n_in; (void)out_size; (void)ws_size;
  const float* x          = (const float*)d_in[0];
  const int*   segment_pos= (const int*)d_in[1];
  const float* w_y        = (const float*)d_in[2];
  const float* b_y        = (const float*)d_in[3];
  const float* w_x        = (const float*)d_in[4];
  const float* b_x        = (const float*)d_in[5];
  const float* w_out      = (const float*)d_in[6];
  const float* b_out      = (const float*)d_in[7];
  const float* conv_w     = (const float*)d_in[8];
  const float* conv_b     = (const float*)d_in[9];
  const float* a_param    = (const float*)d_in[10];
  const float* igate_w    = (const float*)d_in[11];
  const float* igate_b    = (const float*)d_in[12];
  const float* agate_w    = (const float*)d_in[13];
  const float* agate_b    = (const float*)d_in[14];
  float* out = (float*)d_out;

  char* base = (char*)d_ws;
  size_t off = 0;
  auto alloc = [&](size_t nbytes) -> void* {
    void* p = base + off;
    off = (off + nbytes + 255) & ~(size_t)255;
    return p;
  };
  f16*   Xh    = (f16*)alloc((size_t)MTOT * LRU * 2);
  f16*   Yh    = (f16*)alloc((size_t)MTOT * LRU * 2);
  f16*   wyT   = (f16*)alloc((size_t)WID * LRU * 2);
  f16*   wxT   = (f16*)alloc((size_t)WID * LRU * 2);
  f16*   woutT = (f16*)alloc((size_t)LRU * WID * 2);
  f16*   igwT  = (f16*)alloc((size_t)NHEAD * HDIM * HDIM * 2);
  f16*   agwT  = (f16*)alloc((size_t)NHEAD * HDIM * HDIM * 2);
  float* XB    = (float*)alloc((size_t)MTOT * LRU * 4);  // aliased as a_masked later
  f16*   convh = (f16*)alloc((size_t)MTOT * LRU * 2);
  float* normed= (float*)alloc((size_t)MTOT * LRU * 4);
  float* Ac    = (float*)alloc((size_t)BATCH * NC * LRU * 4);
  float* Hc    = (float*)alloc((size_t)BATCH * NC * LRU * 4);
  float* Pc    = (float*)alloc((size_t)BATCH * NC * LRU * 4);
  float* am = XB;   // XB dead after conv_kernel
  f16*   G  = Xh;   // Xh dead after the two input GEMMs

  dim3 tb32(32, 8);
  // cast activations
  cast_f32_f16_kernel<<<(MTOT * LRU / 4 + 255) / 256, 256, 0, stream>>>(x, Xh, MTOT * LRU / 4);
  // weight transposes+casts: [K,N] -> [N,K]
  transpose_cast_kernel<<<dim3(LRU / 32, WID / 32, 1), tb32, 0, stream>>>(w_y, wyT, WID, LRU, 0, 0);
  transpose_cast_kernel<<<dim3(LRU / 32, WID / 32, 1), tb32, 0, stream>>>(w_x, wxT, WID, LRU, 0, 0);
  transpose_cast_kernel<<<dim3(WID / 32, LRU / 32, 1), tb32, 0, stream>>>(w_out, woutT, LRU, WID, 0, 0);
  transpose_cast_kernel<<<dim3(HDIM / 32, HDIM / 32, NHEAD), tb32, 0, stream>>>(
      igate_w, igwT, HDIM, HDIM, (long long)HDIM * HDIM, (long long)HDIM * HDIM);
  transpose_cast_kernel<<<dim3(HDIM / 32, HDIM / 32, NHEAD), tb32, 0, stream>>>(
      agate_w, agwT, HDIM, HDIM, (long long)HDIM * HDIM, (long long)HDIM * HDIM);
  // input GEMMs
  dim3 g1(MTOT / 128, LRU / 128);
  gemm_bt<1><<<g1, 256, 0, stream>>>(Xh, wyT, b_y, nullptr, Yh, MTOT, LRU, WID);
  gemm_bt<0><<<g1, 256, 0, stream>>>(Xh, wxT, b_x, XB, nullptr, MTOT, LRU, WID);
  // causal depthwise conv
  conv_kernel<<<dim3(LRU / 1024, MTOT), 256, 0, stream>>>(XB, conv_w, conv_b, convh);
  // block-diag gates + RG-LRU elementwise
  gates_kernel<<<dim3(MTOT / 128, 2 * NHEAD), 256, 0, stream>>>(
      convh, igwT, agwT, igate_b, agate_b, a_param, segment_pos, am, normed);
  // chunked linear scan
  scan1_kernel<<<dim3(LRU / 256, NC, BATCH), 256, 0, stream>>>(am, normed, Ac, Hc);
  scan2_kernel<<<dim3(LRU / 256, BATCH), 256, 0, stream>>>(Ac, Hc, Pc);
  scan3_kernel<<<dim3(LRU / 256, NC, BATCH), 256, 0, stream>>>(am, normed, Pc, Yh, G);
  // output projection
  gemm_bt<0><<<dim3(MTOT / 128, WID / 128), 256, 0, stream>>>(G, woutT, b_out, out, nullptr,
                                                              MTOT, WID, LRU);
}

// Round 2
// 601.712 us; speedup vs baseline: 1.0727x; 1.0727x over previous
//
#include <hip/hip_runtime.h>
#include <cstdint>
#include <math.h>

typedef _Float16 f16;
typedef f16 f16x8 __attribute__((ext_vector_type(8)));
typedef f16 f16x4 __attribute__((ext_vector_type(4)));
typedef float f32x4 __attribute__((ext_vector_type(4)));

#define BATCH 2
#define TSEQ 4096
#define WID 2048
#define LRU 2048
#define NHEAD 8
#define HDIM 256
#define MTOT (BATCH * TSEQ)   // 8192
#define CT 64                 // scan chunk length
#define NC (TSEQ / CT)        // 64 chunks

// ---------- async global -> LDS, 16B per lane ----------
__device__ __forceinline__ void gl2lds16(const f16* g, f16* l) {
  __builtin_amdgcn_global_load_lds(
      (__attribute__((address_space(1))) uint32_t*)(uintptr_t)g,
      (__attribute__((address_space(3))) uint32_t*)(uint32_t)(uintptr_t)l,
      16, 0, 0);
}

__device__ __forceinline__ float sigmoidf_(float x) { return 1.f / (1.f + expf(-x)); }
__device__ __forceinline__ float f16bits_to_f(uint32_t b) {
  return (float)__builtin_bit_cast(f16, (uint16_t)b);
}

// ---------- elementwise cast fp32 -> f16 (x4 vectorized) ----------
__global__ void cast_f32_f16_kernel(const float* __restrict__ in, f16* __restrict__ out, int n4) {
  int i = blockIdx.x * 256 + threadIdx.x;
  if (i >= n4) return;
  float4 v = ((const float4*)in)[i];
  f16x4 o = { (f16)v.x, (f16)v.y, (f16)v.z, (f16)v.w };
  ((f16x4*)out)[i] = o;
}

// ---------- transpose + cast: in [R,C] fp32 -> out [C,R] f16, batched over z ----------
__global__ void transpose_cast_kernel(const float* __restrict__ in, f16* __restrict__ out,
                                      int R, int C, long long inStride, long long outStride) {
  __shared__ float tile[32][33];
  const float* ib = in + (long long)blockIdx.z * inStride;
  f16* ob = out + (long long)blockIdx.z * outStride;
  int c0 = blockIdx.x * 32, r0 = blockIdx.y * 32;
  int tx = threadIdx.x, ty = threadIdx.y;  // (32,8)
#pragma unroll
  for (int i = 0; i < 32; i += 8)
    tile[ty + i][tx] = ib[(long long)(r0 + ty + i) * C + c0 + tx];
  __syncthreads();
#pragma unroll
  for (int i = 0; i < 32; i += 8)
    ob[(long long)(c0 + ty + i) * R + r0 + tx] = (f16)tile[tx][ty + i];
}

// ---------- fused dual-B input GEMM ----------
// A [M,K], B1T/B2T [N,K] f16. Y = gelu_tanh(A@B1 + b1) f16; X2 = (A@B2 + b2) f16.
__global__ __launch_bounds__(256, 2) void gemm_dual(
    const f16* __restrict__ A, const f16* __restrict__ B1T, const f16* __restrict__ B2T,
    const float* __restrict__ b1, const float* __restrict__ b2,
    f16* __restrict__ Y, f16* __restrict__ X2, int M, int N, int K) {
  __shared__ __align__(16) f16 As[128 * 32];
  __shared__ __align__(16) f16 B1s[128 * 32];
  __shared__ __align__(16) f16 B2s[128 * 32];
  const int m0 = blockIdx.x * 128, n0 = blockIdx.y * 128;
  const int t = threadIdx.x;
  const int lane = t & 63, wave = t >> 6;
  const int wr = (wave >> 1) * 64, wc = (wave & 1) * 64;
  const int l15 = lane & 15, quad = lane >> 4;
  const int srow = t >> 2, scol = (t & 3) * 8;

  const f16* Ag = A + (long long)(m0 + srow) * K + scol;
  const f16* B1g = B1T + (long long)(n0 + srow) * K + scol;
  const f16* B2g = B2T + (long long)(n0 + srow) * K + scol;

  f32x4 c1[4][4] = {};
  f32x4 c2[4][4] = {};
  for (int k0 = 0; k0 < K; k0 += 32) {
    gl2lds16(Ag, &As[t * 8]);   gl2lds16(Ag + (long long)64 * K, &As[64 * 32 + t * 8]);
    gl2lds16(B1g, &B1s[t * 8]); gl2lds16(B1g + (long long)64 * K, &B1s[64 * 32 + t * 8]);
    gl2lds16(B2g, &B2s[t * 8]); gl2lds16(B2g + (long long)64 * K, &B2s[64 * 32 + t * 8]);
    Ag += 32; B1g += 32; B2g += 32;
    __syncthreads();
    f16x8 af[4], b1f[4], b2f[4];
#pragma unroll
    for (int i = 0; i < 4; ++i)
      af[i] = *(const f16x8*)&As[(wr + i * 16 + l15) * 32 + quad * 8];
#pragma unroll
    for (int j = 0; j < 4; ++j) {
      b1f[j] = *(const f16x8*)&B1s[(wc + j * 16 + l15) * 32 + quad * 8];
      b2f[j] = *(const f16x8*)&B2s[(wc + j * 16 + l15) * 32 + quad * 8];
    }
#pragma unroll
    for (int i = 0; i < 4; ++i)
#pragma unroll
      for (int j = 0; j < 4; ++j) {
        c1[i][j] = __builtin_amdgcn_mfma_f32_16x16x32_f16(af[i], b1f[j], c1[i][j], 0, 0, 0);
        c2[i][j] = __builtin_amdgcn_mfma_f32_16x16x32_f16(af[i], b2f[j], c2[i][j], 0, 0, 0);
      }
    __syncthreads();
  }
#pragma unroll
  for (int i = 0; i < 4; ++i) {
#pragma unroll
    for (int j = 0; j < 4; ++j) {
      const int col = n0 + wc + j * 16 + l15;
      const float b1v = b1[col], b2v = b2[col];
      const int row0 = m0 + wr + i * 16 + quad * 4;
#pragma unroll
      for (int r = 0; r < 4; ++r) {
        long long off = (long long)(row0 + r) * N + col;
        float v = c1[i][j][r] + b1v;
        float u = v + 0.044715f * v * v * v;
        float g = 0.5f * v * (1.f + tanhf(0.7978845608028654f * u));
        Y[off] = (f16)g;
        X2[off] = (f16)(c2[i][j][r] + b2v);
      }
    }
  }
}

// ---------- GEMM: C[M,N] = A[M,K] @ BT[N,K]^T + bias (fp32 out) ----------
__global__ __launch_bounds__(256, 2) void gemm_bt(
    const f16* __restrict__ A, const f16* __restrict__ BT, const float* __restrict__ bias,
    float* __restrict__ Cf, int M, int N, int K) {
  __shared__ __align__(16) f16 As[128 * 32];
  __shared__ __align__(16) f16 Bs[128 * 32];
  const int m0 = blockIdx.x * 128, n0 = blockIdx.y * 128;
  const int t = threadIdx.x;
  const int lane = t & 63, wave = t >> 6;
  const int wr = (wave >> 1) * 64, wc = (wave & 1) * 64;
  const int l15 = lane & 15, quad = lane >> 4;
  const int srow = t >> 2, scol = (t & 3) * 8;

  const f16* Ag = A + (long long)(m0 + srow) * K + scol;
  const f16* Bg = BT + (long long)(n0 + srow) * K + scol;

  f32x4 acc[4][4] = {};
  for (int k0 = 0; k0 < K; k0 += 32) {
    gl2lds16(Ag, &As[t * 8]); gl2lds16(Ag + (long long)64 * K, &As[64 * 32 + t * 8]);
    gl2lds16(Bg, &Bs[t * 8]); gl2lds16(Bg + (long long)64 * K, &Bs[64 * 32 + t * 8]);
    Ag += 32; Bg += 32;
    __syncthreads();
    f16x8 af[4], bf[4];
#pragma unroll
    for (int i = 0; i < 4; ++i)
      af[i] = *(const f16x8*)&As[(wr + i * 16 + l15) * 32 + quad * 8];
#pragma unroll
    for (int j = 0; j < 4; ++j)
      bf[j] = *(const f16x8*)&Bs[(wc + j * 16 + l15) * 32 + quad * 8];
#pragma unroll
    for (int i = 0; i < 4; ++i)
#pragma unroll
      for (int j = 0; j < 4; ++j)
        acc[i][j] = __builtin_amdgcn_mfma_f32_16x16x32_f16(af[i], bf[j], acc[i][j], 0, 0, 0);
    __syncthreads();
  }
#pragma unroll
  for (int i = 0; i < 4; ++i) {
#pragma unroll
    for (int j = 0; j < 4; ++j) {
      const int col = n0 + wc + j * 16 + l15;
      const float bv = bias[col];
      const int row0 = m0 + wr + i * 16 + quad * 4;
#pragma unroll
      for (int r = 0; r < 4; ++r)
        Cf[(long long)(row0 + r) * N + col] = acc[i][j][r] + bv;
    }
  }
}

// ---------- causal depthwise temporal conv (TW=4), f16 in -> f16 out ----------
__global__ void conv_kernel(const f16* __restrict__ xb, const float* __restrict__ cw,
                            const float* __restrict__ cb, f16* __restrict__ convh) {
  int l = threadIdx.x * 8;
  int m = blockIdx.x;              // b*T + t
  int tpos = m & (TSEQ - 1);
  float acc[8];
  {
    float4 c0 = *(const float4*)&cb[l];
    float4 c1 = *(const float4*)&cb[l + 4];
    acc[0] = c0.x; acc[1] = c0.y; acc[2] = c0.z; acc[3] = c0.w;
    acc[4] = c1.x; acc[5] = c1.y; acc[6] = c1.z; acc[7] = c1.w;
  }
#pragma unroll
  for (int d = 0; d < 4; ++d) {    // delay d: weight conv_w[3-d]
    if (tpos >= d) {
      f16x8 xv = *(const f16x8*)&xb[(long long)(m - d) * LRU + l];
      float4 w0 = *(const float4*)&cw[(3 - d) * LRU + l];
      float4 w1 = *(const float4*)&cw[(3 - d) * LRU + l + 4];
      acc[0] += w0.x * (float)xv[0]; acc[1] += w0.y * (float)xv[1];
      acc[2] += w0.z * (float)xv[2]; acc[3] += w0.w * (float)xv[3];
      acc[4] += w1.x * (float)xv[4]; acc[5] += w1.y * (float)xv[5];
      acc[6] += w1.z * (float)xv[6]; acc[7] += w1.w * (float)xv[7];
    }
  }
  f16x8 o;
#pragma unroll
  for (int k = 0; k < 8; ++k) o[k] = (f16)acc[k];
  *(f16x8*)&convh[(long long)m * LRU + l] = o;
}

// ---------- block-diag dual gate GEMM + RG-LRU epilogue -> packed (u16 a, f16 normed) ----------
__global__ __launch_bounds__(256, 2) void gates_kernel(
    const f16* __restrict__ Ah, const f16* __restrict__ BiT, const f16* __restrict__ BaT,
    const float* __restrict__ ib, const float* __restrict__ ab,
    const float* __restrict__ a_param, const int* __restrict__ segpos,
    uint32_t* __restrict__ AN) {
  __shared__ __align__(16) f16 As[128 * 32];
  __shared__ __align__(16) f16 Bi[128 * 32];
  __shared__ __align__(16) f16 Ba[128 * 32];
  const int m0 = blockIdx.x * 128;
  const int h = blockIdx.y >> 1;
  const int ncol0 = h * HDIM + (blockIdx.y & 1) * 128;  // global L-col of tile origin
  const int t = threadIdx.x;
  const int lane = t & 63, wave = t >> 6;
  const int wr = (wave >> 1) * 64, wc = (wave & 1) * 64;
  const int l15 = lane & 15, quad = lane >> 4;
  const int srow = t >> 2, scol = (t & 3) * 8;

  const f16* Ag = Ah + (long long)(m0 + srow) * LRU + h * HDIM + scol;
  const f16* Big = BiT + (long long)(ncol0 + srow) * HDIM + scol;
  const f16* Bag = BaT + (long long)(ncol0 + srow) * HDIM + scol;

  f32x4 ci[4][4] = {};
  f32x4 ca[4][4] = {};
  for (int k0 = 0; k0 < HDIM; k0 += 32) {
    gl2lds16(Ag, &As[t * 8]);  gl2lds16(Ag + (long long)64 * LRU, &As[64 * 32 + t * 8]);
    gl2lds16(Big, &Bi[t * 8]); gl2lds16(Big + 64 * HDIM, &Bi[64 * 32 + t * 8]);
    gl2lds16(Bag, &Ba[t * 8]); gl2lds16(Bag + 64 * HDIM, &Ba[64 * 32 + t * 8]);
    Ag += 32; Big += 32; Bag += 32;
    __syncthreads();
    f16x8 af[4], bif[4], baf[4];
#pragma unroll
    for (int i = 0; i < 4; ++i)
      af[i] = *(const f16x8*)&As[(wr + i * 16 + l15) * 32 + quad * 8];
#pragma unroll
    for (int j = 0; j < 4; ++j) {
      bif[j] = *(const f16x8*)&Bi[(wc + j * 16 + l15) * 32 + quad * 8];
      baf[j] = *(const f16x8*)&Ba[(wc + j * 16 + l15) * 32 + quad * 8];
    }
#pragma unroll
    for (int i = 0; i < 4; ++i)
#pragma unroll
      for (int j = 0; j < 4; ++j) {
        ci[i][j] = __builtin_amdgcn_mfma_f32_16x16x32_f16(af[i], bif[j], ci[i][j], 0, 0, 0);
        ca[i][j] = __builtin_amdgcn_mfma_f32_16x16x32_f16(af[i], baf[j], ca[i][j], 0, 0, 0);
      }
    __syncthreads();
  }
#pragma unroll
  for (int i = 0; i < 4; ++i) {
#pragma unroll
    for (int j = 0; j < 4; ++j) {
      const int col = ncol0 + wc + j * 16 + l15;
      const float ibv = ib[col], abv = ab[col];
      const float sp = log1pf(expf(a_param[col]));  // softplus
      const int row0 = m0 + wr + i * 16 + quad * 4;
#pragma unroll
      for (int r = 0; r < 4; ++r) {
        const int row = row0 + r;
        float gx = sigmoidf_(ci[i][j][r] + ibv);
        float ga = sigmoidf_(ca[i][j][r] + abv);
        float la = -8.f * ga * sp;
        bool rs = (segpos[row] == 0);
        float a = rs ? 0.f : expf(la);
        float mult = rs ? 1.f : sqrtf(fmaxf(1.f - expf(2.f * la), 0.f));
        float cv = (float)Ah[(long long)row * LRU + col];
        uint32_t afx = __float2uint_rn(a * 65536.f);
        if (afx > 65535u) afx = 65535u;
        f16 nh = (f16)(cv * gx * mult);
        AN[(long long)row * LRU + col] =
            afx | ((uint32_t)__builtin_bit_cast(uint16_t, nh) << 16);
      }
    }
  }
}

// ---------- chunked scan pass 1: per-chunk (prod a, partial h) ----------
__global__ void scan1_kernel(const uint32_t* __restrict__ AN,
                             float* __restrict__ Ac, float* __restrict__ Hc) {
  int l = blockIdx.x * 256 + threadIdx.x;
  int c = blockIdx.y, b = blockIdx.z;
  long long base = ((long long)b * TSEQ + (long long)c * CT) * LRU + l;
  float A = 1.f, hv = 0.f;
#pragma unroll 8
  for (int s = 0; s < CT; ++s) {
    uint32_t p = AN[base + (long long)s * LRU];
    float a = (float)(p & 0xFFFFu) * (1.f / 65536.f);
    float x = f16bits_to_f(p >> 16);
    A *= a;
    hv = a * hv + x;
  }
  int o = (b * NC + c) * LRU + l;
  Ac[o] = A;
  Hc[o] = hv;
}

// ---------- pass 2: serial prefix over chunks -> carry-in state per chunk ----------
__global__ void scan2_kernel(const float* __restrict__ Ac, const float* __restrict__ Hc,
                             float* __restrict__ P) {
  int l = blockIdx.x * 256 + threadIdx.x;
  int b = blockIdx.y;
  float hv = 0.f;
#pragma unroll 8
  for (int c = 0; c < NC; ++c) {
    int o = (b * NC + c) * LRU + l;
    P[o] = hv;
    hv = Ac[o] * hv + Hc[o];
  }
}

// ---------- pass 3: apply carry, fuse h*y, emit f16 G for final GEMM ----------
__global__ void scan3_kernel(const uint32_t* __restrict__ AN,
                             const float* __restrict__ P, const f16* __restrict__ Yh,
                             f16* __restrict__ G) {
  int l = blockIdx.x * 256 + threadIdx.x;
  int c = blockIdx.y, b = blockIdx.z;
  long long base = ((long long)b * TSEQ + (long long)c * CT) * LRU + l;
  float hv = P[(b * NC + c) * LRU + l];
#pragma unroll 4
  for (int s = 0; s < CT; ++s) {
    long long o = base + (long long)s * LRU;
    uint32_t p = AN[o];
    float a = (float)(p & 0xFFFFu) * (1.f / 65536.f);
    float x = f16bits_to_f(p >> 16);
    hv = a * hv + x;
    G[o] = (f16)(hv * (float)Yh[o]);
  }
}

extern "C" void kernel_launch(void* const* d_in, const int* in_sizes, int n_in,
                              void* d_out, int out_size, void* d_ws, size_t ws_size,
                              hipStream_t stream) {
  (void)in_sizes; (void)n_in; (void)out_size; (void)ws_size;
  const float* x          = (const float*)d_in[0];
  const int*   segment_pos= (const int*)d_in[1];
  const float* w_y        = (const float*)d_in[2];
  const float* b_y        = (const float*)d_in[3];
  const float* w_x        = (const float*)d_in[4];
  const float* b_x        = (const float*)d_in[5];
  const float* w_out      = (const float*)d_in[6];
  const float* b_out      = (const float*)d_in[7];
  const float* conv_w     = (const float*)d_in[8];
  const float* conv_b     = (const float*)d_in[9];
  const float* a_param    = (const float*)d_in[10];
  const float* igate_w    = (const float*)d_in[11];
  const float* igate_b    = (const float*)d_in[12];
  const float* agate_w    = (const float*)d_in[13];
  const float* agate_b    = (const float*)d_in[14];
  float* out = (float*)d_out;

  char* base = (char*)d_ws;
  size_t off = 0;
  auto alloc = [&](size_t nbytes) -> void* {
    void* p = base + off;
    off = (off + nbytes + 255) & ~(size_t)255;
    return p;
  };
  f16*     Xh    = (f16*)alloc((size_t)MTOT * LRU * 2);
  f16*     Yh    = (f16*)alloc((size_t)MTOT * LRU * 2);
  f16*     XBh   = (f16*)alloc((size_t)MTOT * LRU * 2);
  f16*     convh = (f16*)alloc((size_t)MTOT * LRU * 2);
  uint32_t* AN   = (uint32_t*)alloc((size_t)MTOT * LRU * 4);
  f16*     wyT   = (f16*)alloc((size_t)WID * LRU * 2);
  f16*     wxT   = (f16*)alloc((size_t)WID * LRU * 2);
  f16*     woutT = (f16*)alloc((size_t)LRU * WID * 2);
  f16*     igwT  = (f16*)alloc((size_t)NHEAD * HDIM * HDIM * 2);
  f16*     agwT  = (f16*)alloc((size_t)NHEAD * HDIM * HDIM * 2);
  float*   Ac    = (float*)alloc((size_t)BATCH * NC * LRU * 4);
  float*   Hc    = (float*)alloc((size_t)BATCH * NC * LRU * 4);
  float*   Pc    = (float*)alloc((size_t)BATCH * NC * LRU * 4);
  f16*     G     = Xh;   // Xh dead after gemm_dual

  dim3 tb32(32, 8);
  // cast activations
  cast_f32_f16_kernel<<<(MTOT * LRU / 4 + 255) / 256, 256, 0, stream>>>(x, Xh, MTOT * LRU / 4);
  // weight transposes+casts: [K,N] -> [N,K]
  transpose_cast_kernel<<<dim3(LRU / 32, WID / 32, 1), tb32, 0, stream>>>(w_y, wyT, WID, LRU, 0, 0);
  transpose_cast_kernel<<<dim3(LRU / 32, WID / 32, 1), tb32, 0, stream>>>(w_x, wxT, WID, LRU, 0, 0);
  transpose_cast_kernel<<<dim3(WID / 32, LRU / 32, 1), tb32, 0, stream>>>(w_out, woutT, LRU, WID, 0, 0);
  transpose_cast_kernel<<<dim3(HDIM / 32, HDIM / 32, NHEAD), tb32, 0, stream>>>(
      igate_w, igwT, HDIM, HDIM, (long long)HDIM * HDIM, (long long)HDIM * HDIM);
  transpose_cast_kernel<<<dim3(HDIM / 32, HDIM / 32, NHEAD), tb32, 0, stream>>>(
      agate_w, agwT, HDIM, HDIM, (long long)HDIM * HDIM, (long long)HDIM * HDIM);
  // fused dual input GEMM (linear_y + gelu, linear_x)
  gemm_dual<<<dim3(MTOT / 128, LRU / 128), 256, 0, stream>>>(
      Xh, wyT, wxT, b_y, b_x, Yh, XBh, MTOT, LRU, WID);
  // causal depthwise conv (f16 in/out)
  conv_kernel<<<MTOT, 256, 0, stream>>>(XBh, conv_w, conv_b, convh);
  // block-diag gates + RG-LRU elementwise -> packed AN
  gates_kernel<<<dim3(MTOT / 128, 2 * NHEAD), 256, 0, stream>>>(
      convh, igwT, agwT, igate_b, agate_b, a_param, segment_pos, AN);
  // chunked linear scan
  scan1_kernel<<<dim3(LRU / 256, NC, BATCH), 256, 0, stream>>>(AN, Ac, Hc);
  scan2_kernel<<<dim3(LRU / 256, BATCH), 256, 0, stream>>>(Ac, Hc, Pc);
  scan3_kernel<<<dim3(LRU / 256, NC, BATCH), 256, 0, stream>>>(AN, Pc, Yh, G);
  // output projection
  gemm_bt<<<dim3(MTOT / 128, WID / 128), 256, 0, stream>>>(G, woutT, b_out, out, MTOT, WID, LRU);
}

// Round 3
// 573.232 us; speedup vs baseline: 1.1260x; 1.0497x over previous
//
#include <hip/hip_runtime.h>
#include <cstdint>
#include <math.h>

typedef _Float16 f16;
typedef f16 f16x8 __attribute__((ext_vector_type(8)));
typedef f16 f16x4 __attribute__((ext_vector_type(4)));
typedef float f32x4 __attribute__((ext_vector_type(4)));

#define BATCH 2
#define TSEQ 4096
#define WID 2048
#define LRU 2048
#define NHEAD 8
#define HDIM 256
#define MTOT (BATCH * TSEQ)   // 8192
#define CT 128                // scan chunk length == gates m-tile
#define NC (TSEQ / CT)        // 32 chunks

// ---------- async global -> LDS, 16B per lane ----------
__device__ __forceinline__ void gl2lds16(const f16* g, f16* l) {
  __builtin_amdgcn_global_load_lds(
      (__attribute__((address_space(1))) uint32_t*)(uintptr_t)g,
      (__attribute__((address_space(3))) uint32_t*)(uint32_t)(uintptr_t)l,
      16, 0, 0);
}

__device__ __forceinline__ float sigmoidf_(float x) { return 1.f / (1.f + expf(-x)); }
__device__ __forceinline__ float f16bits_to_f(uint32_t b) {
  return (float)__builtin_bit_cast(f16, (uint16_t)b);
}

// ---------- elementwise cast fp32 -> f16 (x4 vectorized) ----------
__global__ void cast_f32_f16_kernel(const float* __restrict__ in, f16* __restrict__ out, int n4) {
  int i = blockIdx.x * 256 + threadIdx.x;
  if (i >= n4) return;
  float4 v = ((const float4*)in)[i];
  f16x4 o = { (f16)v.x, (f16)v.y, (f16)v.z, (f16)v.w };
  ((f16x4*)out)[i] = o;
}

// ---------- merged transpose+cast for the three 2048x2048 weights ----------
__global__ void transpose_big_kernel(const float* __restrict__ s0, const float* __restrict__ s1,
                                     const float* __restrict__ s2, f16* __restrict__ d0,
                                     f16* __restrict__ d1, f16* __restrict__ d2) {
  __shared__ float tile[32][33];
  const int R = 2048, C = 2048;
  const float* ib = blockIdx.z == 0 ? s0 : (blockIdx.z == 1 ? s1 : s2);
  f16* ob = blockIdx.z == 0 ? d0 : (blockIdx.z == 1 ? d1 : d2);
  int c0 = blockIdx.x * 32, r0 = blockIdx.y * 32;
  int tx = threadIdx.x, ty = threadIdx.y;  // (32,8)
#pragma unroll
  for (int i = 0; i < 32; i += 8)
    tile[ty + i][tx] = ib[(long long)(r0 + ty + i) * C + c0 + tx];
  __syncthreads();
#pragma unroll
  for (int i = 0; i < 32; i += 8)
    ob[(long long)(c0 + ty + i) * R + r0 + tx] = (f16)tile[tx][ty + i];
}

// ---------- merged transpose+cast for the 16 gate head blocks (256x256 each) ----------
__global__ void transpose_small_kernel(const float* __restrict__ ig, const float* __restrict__ ag,
                                       f16* __restrict__ igT, f16* __restrict__ agT) {
  __shared__ float tile[32][33];
  int z = blockIdx.z;
  const float* ib = (z < 8 ? ig : ag) + (long long)(z & 7) * HDIM * HDIM;
  f16* ob = (z < 8 ? igT : agT) + (long long)(z & 7) * HDIM * HDIM;
  int c0 = blockIdx.x * 32, r0 = blockIdx.y * 32;
  int tx = threadIdx.x, ty = threadIdx.y;
#pragma unroll
  for (int i = 0; i < 32; i += 8)
    tile[ty + i][tx] = ib[(r0 + ty + i) * HDIM + c0 + tx];
  __syncthreads();
#pragma unroll
  for (int i = 0; i < 32; i += 8)
    ob[(c0 + ty + i) * HDIM + r0 + tx] = (f16)tile[tx][ty + i];
}

// ---------- fused dual-B input GEMM ----------
// A [M,K], B1T/B2T [N,K] f16. Y = gelu_tanh(A@B1 + b1) f16; X2 = (A@B2 + b2) f16.
__global__ __launch_bounds__(256, 2) void gemm_dual(
    const f16* __restrict__ A, const f16* __restrict__ B1T, const f16* __restrict__ B2T,
    const float* __restrict__ b1, const float* __restrict__ b2,
    f16* __restrict__ Y, f16* __restrict__ X2, int M, int N, int K) {
  __shared__ __align__(16) f16 As[128 * 32];
  __shared__ __align__(16) f16 B1s[128 * 32];
  __shared__ __align__(16) f16 B2s[128 * 32];
  const int m0 = blockIdx.x * 128, n0 = blockIdx.y * 128;
  const int t = threadIdx.x;
  const int lane = t & 63, wave = t >> 6;
  const int wr = (wave >> 1) * 64, wc = (wave & 1) * 64;
  const int l15 = lane & 15, quad = lane >> 4;
  const int srow = t >> 2, scol = (t & 3) * 8;

  const f16* Ag = A + (long long)(m0 + srow) * K + scol;
  const f16* B1g = B1T + (long long)(n0 + srow) * K + scol;
  const f16* B2g = B2T + (long long)(n0 + srow) * K + scol;

  f32x4 c1[4][4] = {};
  f32x4 c2[4][4] = {};
  for (int k0 = 0; k0 < K; k0 += 32) {
    gl2lds16(Ag, &As[t * 8]);   gl2lds16(Ag + (long long)64 * K, &As[64 * 32 + t * 8]);
    gl2lds16(B1g, &B1s[t * 8]); gl2lds16(B1g + (long long)64 * K, &B1s[64 * 32 + t * 8]);
    gl2lds16(B2g, &B2s[t * 8]); gl2lds16(B2g + (long long)64 * K, &B2s[64 * 32 + t * 8]);
    Ag += 32; B1g += 32; B2g += 32;
    __syncthreads();
    f16x8 af[4], b1f[4], b2f[4];
#pragma unroll
    for (int i = 0; i < 4; ++i)
      af[i] = *(const f16x8*)&As[(wr + i * 16 + l15) * 32 + quad * 8];
#pragma unroll
    for (int j = 0; j < 4; ++j) {
      b1f[j] = *(const f16x8*)&B1s[(wc + j * 16 + l15) * 32 + quad * 8];
      b2f[j] = *(const f16x8*)&B2s[(wc + j * 16 + l15) * 32 + quad * 8];
    }
#pragma unroll
    for (int i = 0; i < 4; ++i)
#pragma unroll
      for (int j = 0; j < 4; ++j) {
        c1[i][j] = __builtin_amdgcn_mfma_f32_16x16x32_f16(af[i], b1f[j], c1[i][j], 0, 0, 0);
        c2[i][j] = __builtin_amdgcn_mfma_f32_16x16x32_f16(af[i], b2f[j], c2[i][j], 0, 0, 0);
      }
    __syncthreads();
  }
#pragma unroll
  for (int i = 0; i < 4; ++i) {
#pragma unroll
    for (int j = 0; j < 4; ++j) {
      const int col = n0 + wc + j * 16 + l15;
      const float b1v = b1[col], b2v = b2[col];
      const int row0 = m0 + wr + i * 16 + quad * 4;
#pragma unroll
      for (int r = 0; r < 4; ++r) {
        long long off = (long long)(row0 + r) * N + col;
        float v = c1[i][j][r] + b1v;
        float u = v + 0.044715f * v * v * v;
        float g = 0.5f * v * (1.f + tanhf(0.7978845608028654f * u));
        Y[off] = (f16)g;
        X2[off] = (f16)(c2[i][j][r] + b2v);
      }
    }
  }
}

// ---------- GEMM: C[M,N] = A[M,K] @ BT[N,K]^T + bias (fp32 out) ----------
__global__ __launch_bounds__(256, 2) void gemm_bt(
    const f16* __restrict__ A, const f16* __restrict__ BT, const float* __restrict__ bias,
    float* __restrict__ Cf, int M, int N, int K) {
  __shared__ __align__(16) f16 As[128 * 32];
  __shared__ __align__(16) f16 Bs[128 * 32];
  const int m0 = blockIdx.x * 128, n0 = blockIdx.y * 128;
  const int t = threadIdx.x;
  const int lane = t & 63, wave = t >> 6;
  const int wr = (wave >> 1) * 64, wc = (wave & 1) * 64;
  const int l15 = lane & 15, quad = lane >> 4;
  const int srow = t >> 2, scol = (t & 3) * 8;

  const f16* Ag = A + (long long)(m0 + srow) * K + scol;
  const f16* Bg = BT + (long long)(n0 + srow) * K + scol;

  f32x4 acc[4][4] = {};
  for (int k0 = 0; k0 < K; k0 += 32) {
    gl2lds16(Ag, &As[t * 8]); gl2lds16(Ag + (long long)64 * K, &As[64 * 32 + t * 8]);
    gl2lds16(Bg, &Bs[t * 8]); gl2lds16(Bg + (long long)64 * K, &Bs[64 * 32 + t * 8]);
    Ag += 32; Bg += 32;
    __syncthreads();
    f16x8 af[4], bf[4];
#pragma unroll
    for (int i = 0; i < 4; ++i)
      af[i] = *(const f16x8*)&As[(wr + i * 16 + l15) * 32 + quad * 8];
#pragma unroll
    for (int j = 0; j < 4; ++j)
      bf[j] = *(const f16x8*)&Bs[(wc + j * 16 + l15) * 32 + quad * 8];
#pragma unroll
    for (int i = 0; i < 4; ++i)
#pragma unroll
      for (int j = 0; j < 4; ++j)
        acc[i][j] = __builtin_amdgcn_mfma_f32_16x16x32_f16(af[i], bf[j], acc[i][j], 0, 0, 0);
    __syncthreads();
  }
#pragma unroll
  for (int i = 0; i < 4; ++i) {
#pragma unroll
    for (int j = 0; j < 4; ++j) {
      const int col = n0 + wc + j * 16 + l15;
      const float bv = bias[col];
      const int row0 = m0 + wr + i * 16 + quad * 4;
#pragma unroll
      for (int r = 0; r < 4; ++r)
        Cf[(long long)(row0 + r) * N + col] = acc[i][j][r] + bv;
    }
  }
}

// ---------- fused conv + block-diag dual gate GEMM + RG-LRU + chunk summaries ----------
// Block: 128 m-rows (= one scan chunk) x 128 L-cols; head h = blockIdx.y>>1.
// LDS As holds the conv'd A tile [128 x 256] f16, XOR-swizzled 16B granules.
__global__ __launch_bounds__(256, 2) void gates_fused(
    const f16* __restrict__ XBh, const float* __restrict__ cw, const float* __restrict__ cb,
    const f16* __restrict__ BiT, const f16* __restrict__ BaT,
    const float* __restrict__ ib, const float* __restrict__ ab,
    const float* __restrict__ a_param, const int* __restrict__ segpos,
    uint32_t* __restrict__ AN, float* __restrict__ Ac, float* __restrict__ Hc) {
  __shared__ __align__(16) f16 As[128 * 256];   // 64 KB
  __shared__ __align__(16) f16 Bi[128 * 32];    // 8 KB  (reused as carry after k-loop)
  __shared__ __align__(16) f16 Ba[128 * 32];    // 8 KB  -> 80 KB total, 2 blocks/CU
  const int m0 = blockIdx.x * 128;
  const int h = blockIdx.y >> 1;
  const int half = blockIdx.y & 1;
  const int ncol0 = h * HDIM + half * 128;
  const int t = threadIdx.x;
  const int lane = t & 63, wave = t >> 6;
  const int wr = (wave >> 1) * 64, wc = (wave & 1) * 64;
  const int l15 = lane & 15, quad = lane >> 4;

  // ---- conv prologue: As[r][k] = conv(m0+r, h*256+k), swizzled granules ----
#pragma unroll 4
  for (int it = 0; it < 16; ++it) {
    int idx = it * 256 + t;
    int r = idx >> 5, kc = idx & 31;          // granule kc = 8 f16 = 16 B
    int m = m0 + r, tpos = m & (TSEQ - 1);
    int colbase = h * HDIM + kc * 8;
    float acc[8];
    {
      float4 c0 = *(const float4*)&cb[colbase];
      float4 c1 = *(const float4*)&cb[colbase + 4];
      acc[0] = c0.x; acc[1] = c0.y; acc[2] = c0.z; acc[3] = c0.w;
      acc[4] = c1.x; acc[5] = c1.y; acc[6] = c1.z; acc[7] = c1.w;
    }
#pragma unroll
    for (int d = 0; d < 4; ++d) {
      if (tpos >= d) {
        f16x8 xv = *(const f16x8*)&XBh[(long long)(m - d) * LRU + colbase];
        float4 w0 = *(const float4*)&cw[(3 - d) * LRU + colbase];
        float4 w1 = *(const float4*)&cw[(3 - d) * LRU + colbase + 4];
        acc[0] += w0.x * (float)xv[0]; acc[1] += w0.y * (float)xv[1];
        acc[2] += w0.z * (float)xv[2]; acc[3] += w0.w * (float)xv[3];
        acc[4] += w1.x * (float)xv[4]; acc[5] += w1.y * (float)xv[5];
        acc[6] += w1.z * (float)xv[6]; acc[7] += w1.w * (float)xv[7];
      }
    }
    f16x8 o;
#pragma unroll
    for (int k = 0; k < 8; ++k) o[k] = (f16)acc[k];
    int gs = (kc & ~7) | ((kc ^ r) & 7);      // XOR bank-group swizzle
    *(f16x8*)&As[r * 256 + gs * 8] = o;
  }
  __syncthreads();

  // ---- dual GEMM k-loop over the head's 256 k-cols ----
  const int srow = t >> 2, scol = (t & 3) * 8;
  const f16* Big = BiT + (long long)(ncol0 + srow) * HDIM + scol;
  const f16* Bag = BaT + (long long)(ncol0 + srow) * HDIM + scol;
  f32x4 ci[4][4] = {};
  f32x4 ca[4][4] = {};
  for (int k0 = 0; k0 < HDIM; k0 += 32) {
    gl2lds16(Big, &Bi[t * 8]); gl2lds16(Big + 64 * HDIM, &Bi[64 * 32 + t * 8]);
    gl2lds16(Bag, &Ba[t * 8]); gl2lds16(Bag + 64 * HDIM, &Ba[64 * 32 + t * 8]);
    Big += 32; Bag += 32;
    __syncthreads();
    f16x8 af[4], bif[4], baf[4];
#pragma unroll
    for (int i = 0; i < 4; ++i) {
      int row = wr + i * 16 + l15;
      int g = (k0 >> 3) + quad;
      int gsw = (g & ~7) | ((g ^ row) & 7);
      af[i] = *(const f16x8*)&As[row * 256 + gsw * 8];
    }
#pragma unroll
    for (int j = 0; j < 4; ++j) {
      bif[j] = *(const f16x8*)&Bi[(wc + j * 16 + l15) * 32 + quad * 8];
      baf[j] = *(const f16x8*)&Ba[(wc + j * 16 + l15) * 32 + quad * 8];
    }
#pragma unroll
    for (int i = 0; i < 4; ++i)
#pragma unroll
      for (int j = 0; j < 4; ++j) {
        ci[i][j] = __builtin_amdgcn_mfma_f32_16x16x32_f16(af[i], bif[j], ci[i][j], 0, 0, 0);
        ca[i][j] = __builtin_amdgcn_mfma_f32_16x16x32_f16(af[i], baf[j], ca[i][j], 0, 0, 0);
      }
    __syncthreads();
  }

  // ---- epilogue: RG-LRU elementwise, pack AN, and per-column chunk summaries ----
  const int mb = m0 >> 12;                 // batch index (4096 rows/batch)
  const int cch = (m0 & (TSEQ - 1)) >> 7;  // chunk within batch
  float Aw[4], hw[4];                      // per-j wave-level (64-row) summaries
#pragma unroll
  for (int j = 0; j < 4; ++j) {
    const int cl = wc + j * 16 + l15;      // tile-local col 0..127
    const int col = ncol0 + cl;
    const float ibv = ib[col], abv = ab[col];
    const float sp = log1pf(expf(a_param[col]));
    float A4[4], h4[4];
#pragma unroll
    for (int i = 0; i < 4; ++i) {
      float Aseg = 1.f, hseg = 0.f;
#pragma unroll
      for (int r = 0; r < 4; ++r) {
        const int rowL = wr + i * 16 + quad * 4 + r;
        const int row = m0 + rowL;
        float gx = sigmoidf_(ci[i][j][r] + ibv);
        float ga = sigmoidf_(ca[i][j][r] + abv);
        float la = -8.f * ga * sp;
        bool rs = (segpos[row] == 0);
        float a = rs ? 0.f : expf(la);
        uint32_t afx = __float2uint_rn(a * 65536.f);
        if (afx > 65535u) afx = 65535u;
        float aq = (float)afx * (1.f / 65536.f);
        // conv value from swizzled LDS
        int cfull = half * 128 + cl;
        int g = cfull >> 3, e = cfull & 7;
        int gsw = (g & ~7) | ((g ^ rowL) & 7);
        float cv = (float)As[rowL * 256 + gsw * 8 + e];
        float mult = rs ? 1.f : sqrtf(fmaxf(1.f - aq * aq, 0.f));
        f16 nh = (f16)(cv * gx * mult);
        AN[(long long)row * LRU + col] =
            afx | ((uint32_t)__builtin_bit_cast(uint16_t, nh) << 16);
        float xq = (float)nh;
        hseg = aq * hseg + xq;   // scan over r (rows ascending)
        Aseg *= aq;
      }
      A4[i] = Aseg; h4[i] = hseg;
    }
    // cross-quad composition (rows quad*4.. ascending), Kogge-Stone over stride-16 lanes
#pragma unroll
    for (int i = 0; i < 4; ++i) {
      float A = A4[i], hv = h4[i];
#pragma unroll
      for (int d = 1; d <= 2; d <<= 1) {
        int src = quad >= d ? lane - 16 * d : lane;
        float Ap = __shfl(A, src);
        float hp = __shfl(hv, src);
        if (quad >= d) { hv = A * hp + hv; A = Ap * A; }
      }
      A4[i] = __shfl(A, 48 + l15);   // 16-row block total (from quad 3)
      h4[i] = __shfl(hv, 48 + l15);
    }
    float Awv = 1.f, hwv = 0.f;
#pragma unroll
    for (int i = 0; i < 4; ++i) { hwv = A4[i] * hwv + h4[i]; Awv *= A4[i]; }
    Aw[j] = Awv; hw[j] = hwv;
  }
  // cross-wave composition via LDS (reuse Bi space; k-loop is done)
  float* carry = (float*)Bi;   // [128 cols][2]
  __syncthreads();
  if (wr == 0 && quad == 0) {
#pragma unroll
    for (int j = 0; j < 4; ++j) {
      int cl = wc + j * 16 + l15;
      carry[cl * 2] = Aw[j]; carry[cl * 2 + 1] = hw[j];
    }
  }
  __syncthreads();
  if (wr == 64 && quad == 0) {
#pragma unroll
    for (int j = 0; j < 4; ++j) {
      int cl = wc + j * 16 + l15;
      float At = carry[cl * 2], ht = carry[cl * 2 + 1];
      float A = At * Aw[j];
      float hv = Aw[j] * ht + hw[j];
      int o = (mb * NC + cch) * LRU + ncol0 + cl;
      Ac[o] = A; Hc[o] = hv;
    }
  }
}

// ---------- pass 2: serial prefix over chunks -> carry-in state per chunk ----------
__global__ void scan2_kernel(const float* __restrict__ Ac, const float* __restrict__ Hc,
                             float* __restrict__ P) {
  int l = blockIdx.x * 256 + threadIdx.x;
  int b = blockIdx.y;
  float hv = 0.f;
#pragma unroll 8
  for (int c = 0; c < NC; ++c) {
    int o = (b * NC + c) * LRU + l;
    P[o] = hv;
    hv = Ac[o] * hv + Hc[o];
  }
}

// ---------- pass 3: apply carry, fuse h*y, emit f16 G for final GEMM ----------
__global__ void scan3_kernel(const uint32_t* __restrict__ AN,
                             const float* __restrict__ P, const f16* __restrict__ Yh,
                             f16* __restrict__ G) {
  int l = blockIdx.x * 256 + threadIdx.x;
  int c = blockIdx.y, b = blockIdx.z;
  long long base = ((long long)b * TSEQ + (long long)c * CT) * LRU + l;
  float hv = P[(b * NC + c) * LRU + l];
#pragma unroll 4
  for (int s = 0; s < CT; ++s) {
    long long o = base + (long long)s * LRU;
    uint32_t p = AN[o];
    float a = (float)(p & 0xFFFFu) * (1.f / 65536.f);
    float x = f16bits_to_f(p >> 16);
    hv = a * hv + x;
    G[o] = (f16)(hv * (float)Yh[o]);
  }
}

extern "C" void kernel_launch(void* const* d_in, const int* in_sizes, int n_in,
                              void* d_out, int out_size, void* d_ws, size_t ws_size,
                              hipStream_t stream) {
  (void)in_sizes; (void)n_in; (void)out_size; (void)ws_size;
  const float* x          = (const float*)d_in[0];
  const int*   segment_pos= (const int*)d_in[1];
  const float* w_y        = (const float*)d_in[2];
  const float* b_y        = (const float*)d_in[3];
  const float* w_x        = (const float*)d_in[4];
  const float* b_x        = (const float*)d_in[5];
  const float* w_out      = (const float*)d_in[6];
  const float* b_out      = (const float*)d_in[7];
  const float* conv_w     = (const float*)d_in[8];
  const float* conv_b     = (const float*)d_in[9];
  const float* a_param    = (const float*)d_in[10];
  const float* igate_w    = (const float*)d_in[11];
  const float* igate_b    = (const float*)d_in[12];
  const float* agate_w    = (const float*)d_in[13];
  const float* agate_b    = (const float*)d_in[14];
  float* out = (float*)d_out;

  char* base = (char*)d_ws;
  size_t off = 0;
  auto alloc = [&](size_t nbytes) -> void* {
    void* p = base + off;
    off = (off + nbytes + 255) & ~(size_t)255;
    return p;
  };
  f16*     Xh    = (f16*)alloc((size_t)MTOT * LRU * 2);
  f16*     Yh    = (f16*)alloc((size_t)MTOT * LRU * 2);
  f16*     XBh   = (f16*)alloc((size_t)MTOT * LRU * 2);
  uint32_t* AN   = (uint32_t*)alloc((size_t)MTOT * LRU * 4);
  f16*     wyT   = (f16*)alloc((size_t)WID * LRU * 2);
  f16*     wxT   = (f16*)alloc((size_t)WID * LRU * 2);
  f16*     woutT = (f16*)alloc((size_t)LRU * WID * 2);
  f16*     igwT  = (f16*)alloc((size_t)NHEAD * HDIM * HDIM * 2);
  f16*     agwT  = (f16*)alloc((size_t)NHEAD * HDIM * HDIM * 2);
  float*   Ac    = (float*)alloc((size_t)BATCH * NC * LRU * 4);
  float*   Hc    = (float*)alloc((size_t)BATCH * NC * LRU * 4);
  float*   Pc    = (float*)alloc((size_t)BATCH * NC * LRU * 4);
  f16*     G     = Xh;   // Xh dead after gemm_dual

  dim3 tb32(32, 8);
  // cast activations
  cast_f32_f16_kernel<<<(MTOT * LRU / 4 + 255) / 256, 256, 0, stream>>>(x, Xh, MTOT * LRU / 4);
  // weight transposes+casts (merged)
  transpose_big_kernel<<<dim3(64, 64, 3), tb32, 0, stream>>>(w_y, w_x, w_out, wyT, wxT, woutT);
  transpose_small_kernel<<<dim3(8, 8, 16), tb32, 0, stream>>>(igate_w, agate_w, igwT, agwT);
  // fused dual input GEMM (linear_y + gelu, linear_x)
  gemm_dual<<<dim3(MTOT / 128, LRU / 128), 256, 0, stream>>>(
      Xh, wyT, wxT, b_y, b_x, Yh, XBh, MTOT, LRU, WID);
  // fused conv + gates + RG-LRU + chunk summaries
  gates_fused<<<dim3(MTOT / 128, 2 * NHEAD), 256, 0, stream>>>(
      XBh, conv_w, conv_b, igwT, agwT, igate_b, agate_b, a_param, segment_pos, AN, Ac, Hc);
  // chunk-carry prefix + final scan
  scan2_kernel<<<dim3(LRU / 256, BATCH), 256, 0, stream>>>(Ac, Hc, Pc);
  scan3_kernel<<<dim3(LRU / 256, NC, BATCH), 256, 0, stream>>>(AN, Pc, Yh, G);
  // output projection
  gemm_bt<<<dim3(MTOT / 128, WID / 128), 256, 0, stream>>>(G, woutT, b_out, out, MTOT, WID, LRU);
}